// Round 3
// baseline (589.824 us; speedup 1.0000x reference)
//
#include <hip/hip_runtime.h>
#include <hip/hip_bf16.h>

#define H_ 4
#define B_ 16
#define T_ 4000
#define E_ 512
#define D_ 512
#define A_ 128
#define C_ 10
#define K_ 101
#define O_ 512
#define TC_ 50
#define CH_ (T_ / TC_)   // 80

typedef __attribute__((ext_vector_type(16))) float f32x16;
typedef __attribute__((ext_vector_type(8)))  short short8;

#define MFMA32(a, b, c) __builtin_amdgcn_mfma_f32_32x32x16_bf16(a, b, c, 0, 0, 0)

#define GLL16(gp, lp) __builtin_amdgcn_global_load_lds( \
    (const __attribute__((address_space(1))) unsigned int*)(gp), \
    (__attribute__((address_space(3))) unsigned int*)(lp), 16, 0, 0)

static __device__ __forceinline__ unsigned short f2bf(float x) {
  unsigned u = __float_as_uint(x);
  unsigned r = (u + 0x7FFFu + ((u >> 16) & 1u)) >> 16;
  return (unsigned short)r;
}
static __device__ __forceinline__ unsigned pk2(float a, float b) {
  return (unsigned)f2bf(a) | ((unsigned)f2bf(b) << 16);
}
// HW packed cvt (v_cvt_pk_bf16_f32), RNE — same rounding as f2bf
static __device__ __forceinline__ unsigned pkcvt(float a, float b) {
  __hip_bfloat162 h2 = __float22bfloat162_rn(make_float2(a, b));
  unsigned u; __builtin_memcpy(&u, &h2, 4); return u;
}
static __device__ __forceinline__ uint4 packbf8(float4 f0, float4 f1) {
  uint4 u;
  u.x = pkcvt(f0.x, f0.y); u.y = pkcvt(f0.z, f0.w);
  u.z = pkcvt(f1.x, f1.y); u.w = pkcvt(f1.z, f1.w);
  return u;
}
static __device__ __forceinline__ f32x16 zero16() {
  f32x16 z;
#pragma unroll
  for (int i = 0; i < 16; ++i) z[i] = 0.f;
  return z;
}
static __device__ __forceinline__ float tanh_fast(float x) {
  return 1.0f - 2.0f / (__expf(2.0f * x) + 1.0f);
}
// swizzled byte offset for 32-k-wide bf16 tiles packed as 2 rows per 128B line
static __device__ __forceinline__ int swz32(int r, int ksg) {
  return (r >> 1) * 128 + (((((r & 1) << 2) | ksg) ^ ((r >> 1) & 7)) << 4);
}
// swizzled byte offset for 64-elem-wide bf16 rows (128B per row)
static __device__ __forceinline__ int swzC(int r, int sl) {
  return r * 128 + ((sl ^ (r & 7)) << 4);
}

// ---------------------------------------------------------------------------
// k_prep: (a) wbs  = pre-swizzled bf16 Wenc [16 kt][512 n][32 k]  (512 KB)
//         (b) wattb = pre-swizzled bf16 padded Watt                (16 KB)
//         (c) addv4[p][b][h][a] = 4-way split-K partials of benc + dec_z@Wdec
__global__ __launch_bounds__(256) void k_prep(const float* __restrict__ Wenc,
                                              const float* __restrict__ Watt,
                                              const float* __restrict__ dec_z,
                                              const float* __restrict__ Wdec,
                                              const float* __restrict__ benc,
                                              char* __restrict__ wbs,
                                              char* __restrict__ wattb,
                                              float* __restrict__ addv4) {
  const int bid = blockIdx.x;
  const int tid = threadIdx.x;
  if (bid < 128) {
    const int c = bid * 256 + tid;          // 16B chunk index into wbs
    const int cc = c & 2047;
    const int kt = c >> 11;
    const int line = cc >> 3, sp = cc & 7;
    const int sraw = sp ^ (line & 7);
    const int n = line * 2 + (sraw >> 2);
    const int ksg = sraw & 3;
    const int h = n >> 7, a = n & 127;
    const int kb = kt * 32 + ksg * 8;
    uint4 u;
    u.x = pk2(Wenc[((size_t)h * E_ + kb + 0) * A_ + a], Wenc[((size_t)h * E_ + kb + 1) * A_ + a]);
    u.y = pk2(Wenc[((size_t)h * E_ + kb + 2) * A_ + a], Wenc[((size_t)h * E_ + kb + 3) * A_ + a]);
    u.z = pk2(Wenc[((size_t)h * E_ + kb + 4) * A_ + a], Wenc[((size_t)h * E_ + kb + 5) * A_ + a]);
    u.w = pk2(Wenc[((size_t)h * E_ + kb + 6) * A_ + a], Wenc[((size_t)h * E_ + kb + 7) * A_ + a]);
    ((uint4*)wbs)[c] = u;
  } else if (bid == 128) {
#pragma unroll
    for (int q = 0; q < 4; ++q) {
      const int cw = q * 256 + tid;         // 1024 chunks
      const int h = cw >> 8, cc = cw & 255;
      const int line = cc >> 3, sp = cc & 7;
      const int sraw = sp ^ (line & 7);
      const int a = line * 4 + (sraw >> 1);
      const int s = sraw & 1;
      unsigned short v[8];
#pragma unroll
      for (int j = 0; j < 8; ++j) {
        const int k = s * 8 + j;
        v[j] = (k < C_) ? f2bf(Watt[((size_t)h * C_ + k) * A_ + a]) : (unsigned short)0;
      }
      uint4 u;
      u.x = (unsigned)v[0] | ((unsigned)v[1] << 16);
      u.y = (unsigned)v[2] | ((unsigned)v[3] << 16);
      u.z = (unsigned)v[4] | ((unsigned)v[5] << 16);
      u.w = (unsigned)v[6] | ((unsigned)v[7] << 16);
      ((uint4*)wattb)[cw] = u;
    }
  } else {
    // addv split-K: blocks 129..256 -> idx 0..127 = (b, h, ks)
    const int idx = bid - 129;
    const int b = idx >> 3, h = (idx >> 1) & 3, ks = idx & 1;
    const int a = tid & 127, kh = tid >> 7;
    const int p = ks * 2 + kh;              // partial id 0..3
    const int d0 = p * 128;
    const float* z = dec_z + (size_t)b * D_ + d0;
    const float* w = Wdec + ((size_t)h * D_ + d0) * A_ + a;
    float s = (p == 0) ? benc[h * A_ + a] : 0.f;
#pragma unroll 8
    for (int d = 0; d < 128; ++d) s += z[d] * w[(size_t)d * A_];
    addv4[(((size_t)p * B_ + b) * H_ + h) * A_ + a] = s;
  }
}

// ---------------------------------------------------------------------------
// conv features, bf16, padded: convpad[row=b*T+t][h*16 + c], c in [0,16)
__global__ __launch_bounds__(256) void k_conv(const float* __restrict__ att_prev,
                                              const float* __restrict__ conv_w,
                                              char* __restrict__ convpad) {
  const int bh = blockIdx.x;
  const int b = bh / H_, h = bh % H_;
  const int t0 = blockIdx.y * 256;
  __shared__ float ap[256 + K_ - 1 + 3];
  __shared__ float cw[C_ * K_];
  const float* src = att_prev + ((size_t)h * B_ + b) * T_;
  for (int i = threadIdx.x; i < 256 + K_ - 1; i += 256) {
    int tt = t0 - (K_ / 2) + i;
    ap[i] = (tt >= 0 && tt < T_) ? src[tt] : 0.f;
  }
  for (int i = threadIdx.x; i < C_ * K_; i += 256) cw[i] = conv_w[(size_t)h * C_ * K_ + i];
  __syncthreads();
  const int t = t0 + threadIdx.x;
  if (t < T_) {
    float s[C_];
#pragma unroll
    for (int c = 0; c < C_; ++c) s[c] = 0.f;
    for (int k = 0; k < K_; ++k) {
      float apv = ap[threadIdx.x + k];
#pragma unroll
      for (int c = 0; c < C_; ++c) s[c] += cw[c * K_ + k] * apv;
    }
    uint4 u0, u1;
    u0.x = pk2(s[0], s[1]); u0.y = pk2(s[2], s[3]);
    u0.z = pk2(s[4], s[5]); u0.w = pk2(s[6], s[7]);
    u1.x = pk2(s[8], s[9]); u1.y = 0u; u1.z = 0u; u1.w = 0u;
    char* dst = convpad + (size_t)(b * T_ + t) * 128 + h * 32;
    *(uint4*)dst = u0;
    *(uint4*)(dst + 16) = u1;
  }
}

// ---------------------------------------------------------------------------
// Fused MFMA: e[b,h,t] = sum_a gv[h,a]*tanh( enc@Wenc + conv@Watt + addv )
// Block: 128 rows x 512 cols (8 waves: wm 0..1 x head 0..3), BK=32, 16 kt + conv
__global__ __launch_bounds__(512, 4) void k_fused_e_mfma(
    const float* __restrict__ enc,
    const char*  __restrict__ wbs,
    const char*  __restrict__ convpad,
    const char*  __restrict__ wattb,
    const float* __restrict__ addv4,
    const float* __restrict__ gv,
    float* __restrict__ e_out) {
  __shared__ char smem[81920];
  const int ABUF0o = 0, ABUF1o = 8192, BBUF0o = 16384, BBUF1o = 49152;
  const int tid = threadIdx.x;
  const int wv = tid >> 6;
  const int wh = wv & 3;        // head
  const int wm = wv >> 2;       // M-half (rows wm*64 .. +63)
  const int lane = tid & 63;
  const int ln31 = lane & 31;
  const int hi = lane >> 5;
  const int m0 = blockIdx.x * 128;
  const unsigned b0 = (unsigned)m0 / 4000u;
  const unsigned b1 = (unsigned)(m0 + 127) / 4000u;

  f32x16 acc[2][4];
#pragma unroll
  for (int i = 0; i < 2; ++i)
#pragma unroll
    for (int j = 0; j < 4; ++j) acc[i][j] = zero16();

  // staging geometry
  const int srow = tid >> 2, sksg = tid & 3;     // A: 4 threads/row, 32B each
  const int stA = swz32(srow, sksg);
  const float* encRow = enc + (size_t)(m0 + srow) * E_ + sksg * 8;
  const int wbase = wv * 1024;
  const int lof = lane * 16;

  // ---- prologue: stage K-tile 0
  {
    float4 f0 = ((const float4*)encRow)[0];
    float4 f1 = ((const float4*)encRow)[1];
    *(uint4*)(smem + ABUF0o + stA) = packbf8(f0, f1);
#pragma unroll
    for (int it = 0; it < 4; ++it)
      GLL16(wbs + (size_t)it * 8192 + wbase + lof, smem + BBUF0o + it * 8192 + wbase);
  }
  __syncthreads();

  for (int kt = 0; kt < 16; ++kt) {
    const int cur = kt & 1;
    const char* Ab = smem + (cur ? ABUF1o : ABUF0o);
    const char* Bb = smem + (cur ? BBUF1o : BBUF0o);
    char* An = smem + (cur ? ABUF0o : ABUF1o);
    char* Bn = smem + (cur ? BBUF0o : BBUF1o);

    uint4 pk = {0, 0, 0, 0};
    uint4 rc0 = {0, 0, 0, 0}, rc1 = {0, 0, 0, 0};
    float av0s = 0.f, av1s = 0.f, gvv = 0.f;

    if (kt < 15) {
      const float* apk = encRow + (kt + 1) * 32;
      float4 f0 = ((const float4*)apk)[0];
      float4 f1 = ((const float4*)apk)[1];
      pk = packbf8(f0, f1);
#pragma unroll
      for (int it = 0; it < 4; ++it)
        GLL16(wbs + (size_t)(kt + 1) * 32768 + it * 8192 + wbase + lof,
              Bn + it * 8192 + wbase);
    } else {
      // conv A-tile (16KB, reg roundtrip), Watt (16KB via GLL), addv sums, gv
      rc0 = *(const uint4*)(convpad + (size_t)(m0 + (tid >> 3)) * 128 + (tid & 7) * 16);
      rc1 = *(const uint4*)(convpad + (size_t)(m0 + ((tid + 512) >> 3)) * 128 + (tid & 7) * 16);
#pragma unroll
      for (int it = 0; it < 2; ++it)
        GLL16(wattb + (size_t)it * 8192 + wbase + lof, Bn + 16384 + it * 8192 + wbase);
      av0s = addv4[b0 * 512 + tid]        + addv4[8192 + b0 * 512 + tid]
           + addv4[16384 + b0 * 512 + tid] + addv4[24576 + b0 * 512 + tid];
      av1s = addv4[b1 * 512 + tid]        + addv4[8192 + b1 * 512 + tid]
           + addv4[16384 + b1 * 512 + tid] + addv4[24576 + b1 * 512 + tid];
      gvv = gv[tid];
    }

    // ---- compute on current buffers
#pragma unroll
    for (int kc = 0; kc < 2; ++kc) {
      const int ksg = kc * 2 + hi;
      short8 a0 = *(const short8*)(Ab + swz32(wm * 64 + ln31, ksg));
      short8 a1 = *(const short8*)(Ab + swz32(wm * 64 + 32 + ln31, ksg));
#pragma unroll
      for (int ni = 0; ni < 4; ++ni) {
        const int n = wh * 128 + ni * 32 + ln31;
        short8 bfr = *(const short8*)(Bb + swz32(n, ksg));
        acc[0][ni] = MFMA32(a0, bfr, acc[0][ni]);
        acc[1][ni] = MFMA32(a1, bfr, acc[1][ni]);
      }
    }

    if (kt < 15) {
      *(uint4*)(An + stA) = pk;
    } else {
      *(uint4*)(Bn + swzC(tid >> 3, tid & 7)) = rc0;
      *(uint4*)(Bn + swzC((tid + 512) >> 3, tid & 7)) = rc1;
      ((float*)An)[tid] = av0s;
      ((float*)An)[512 + tid] = av1s;
      ((float*)An)[1024 + tid] = gvv;
    }
    __syncthreads();
  }

  // ---- conv MFMA step (K=16): A = conv features, B = Watt
  {
    const char* AconvL = smem + BBUF0o;
    const char* WattL  = smem + BBUF0o + 16384;
    const int sl = wh * 2 + hi;
    short8 ac0 = *(const short8*)(AconvL + swzC(wm * 64 + ln31, sl));
    short8 ac1 = *(const short8*)(AconvL + swzC(wm * 64 + 32 + ln31, sl));
#pragma unroll
    for (int ni = 0; ni < 4; ++ni) {
      const int a = ni * 32 + ln31;
      short8 wf = *(const short8*)(WattL + wh * 4096 + (a >> 2) * 128 +
                                   (((((a & 3) << 1) | hi) ^ ((a >> 2) & 7)) << 4));
      acc[0][ni] = MFMA32(ac0, wf, acc[0][ni]);
      acc[1][ni] = MFMA32(ac1, wf, acc[1][ni]);
    }
  }

  // ---- epilogue
  {
    const float* An_f = (const float*)(smem + ABUF0o);
    float av0[4], av1[4], gvr[4];
#pragma unroll
    for (int ni = 0; ni < 4; ++ni) {
      const int a = wh * 128 + ni * 32 + ln31;
      av0[ni] = An_f[a];
      av1[ni] = An_f[512 + a];
      gvr[ni] = An_f[1024 + a];
    }
#pragma unroll
    for (int mi = 0; mi < 2; ++mi) {
#pragma unroll
      for (int reg = 0; reg < 16; ++reg) {
        const int rl = wm * 64 + mi * 32 + (reg & 3) + ((reg >> 2) << 3) + (hi << 2);
        const unsigned brow = (unsigned)(m0 + rl);
        const unsigned bb = brow / 4000u;
        const unsigned tt = brow - bb * 4000u;
        const int sel = (bb != b0);
        float rs = 0.f;
#pragma unroll
        for (int ni = 0; ni < 4; ++ni) {
          float s = acc[mi][ni][reg] + (sel ? av1[ni] : av0[ni]);
          rs += gvr[ni] * tanh_fast(s);
        }
        rs += __shfl_xor(rs, 1);
        rs += __shfl_xor(rs, 2);
        rs += __shfl_xor(rs, 4);
        rs += __shfl_xor(rs, 8);
        rs += __shfl_xor(rs, 16);
        if (ln31 == 0) e_out[((size_t)bb * H_ + wh) * T_ + tt] = rs;
      }
    }
  }
}

// ---------------------------------------------------------------------------
// per-(b,h) softmax stats: msum[bh] = (max, 1/sum)
__global__ __launch_bounds__(256) void k_msum(const float* __restrict__ e_in,
                                              float2* __restrict__ msum) {
  const int bh = blockIdx.x;
  const float* er = e_in + (size_t)bh * T_;
  __shared__ float red[256];
  const int tid = threadIdx.x;
  float m = -1e30f;
  for (int t = tid; t < T_; t += 256) m = fmaxf(m, er[t]);
  red[tid] = m;
  __syncthreads();
  for (int s = 128; s > 0; s >>= 1) {
    if (tid < s) red[tid] = fmaxf(red[tid], red[tid + s]);
    __syncthreads();
  }
  m = red[0];
  __syncthreads();
  float sum = 0.f;
  for (int t = tid; t < T_; t += 256) sum += __expf(er[t] - m);
  red[tid] = sum;
  __syncthreads();
  for (int s = 128; s > 0; s >>= 1) {
    if (tid < s) red[tid] += red[tid + s];
    __syncthreads();
  }
  if (tid == 0) msum[bh] = make_float2(m, 1.0f / red[0]);
}

// ---------------------------------------------------------------------------
// ctx + inline softmax: computes w = exp(e-m)/sum, writes ws output AND
// context partials partial[tc][b][h][E] for its 80-row chunk. float4 enc loads.
__global__ __launch_bounds__(128) void k_ctx(const float* __restrict__ enc,
                                             const float* __restrict__ e_in,
                                             const float2* __restrict__ msum,
                                             float* __restrict__ wout,
                                             float* __restrict__ partial) {
  const int b = blockIdx.x, tc = blockIdx.y;
  const int t0 = tc * CH_;
  const int tid = threadIdx.x;
  __shared__ float wls[H_ * CH_];
  for (int i = tid; i < H_ * CH_; i += 128) {
    const int h = i / CH_, tt = i - h * CH_;
    const float2 ms = msum[b * H_ + h];
    const float w = __expf(e_in[((size_t)b * H_ + h) * T_ + t0 + tt] - ms.x) * ms.y;
    wls[i] = w;
    wout[((size_t)h * B_ + b) * T_ + t0 + tt] = w;
  }
  __syncthreads();
  float4 a0 = {0,0,0,0}, a1 = {0,0,0,0}, a2 = {0,0,0,0}, a3 = {0,0,0,0};
  const float4* enc4 = (const float4*)enc;
  const size_t ebase = ((size_t)b * T_ + t0) * 128 + tid;   // float4 units, E/4=128
#pragma unroll 4
  for (int tt = 0; tt < CH_; ++tt) {
    const float4 x = enc4[ebase + (size_t)tt * 128];
    const float w0 = wls[tt], w1 = wls[CH_ + tt], w2 = wls[2 * CH_ + tt], w3 = wls[3 * CH_ + tt];
    a0.x += w0 * x.x; a0.y += w0 * x.y; a0.z += w0 * x.z; a0.w += w0 * x.w;
    a1.x += w1 * x.x; a1.y += w1 * x.y; a1.z += w1 * x.z; a1.w += w1 * x.w;
    a2.x += w2 * x.x; a2.y += w2 * x.y; a2.z += w2 * x.z; a2.w += w2 * x.w;
    a3.x += w3 * x.x; a3.y += w3 * x.y; a3.z += w3 * x.z; a3.w += w3 * x.w;
  }
  float4* p4 = (float4*)partial;
  const size_t pbase = (((size_t)tc * B_ + b) * H_) * 128 + tid;
  p4[pbase] = a0;
  p4[pbase + 128] = a1;
  p4[pbase + 256] = a2;
  p4[pbase + 384] = a3;
}

// ---------------------------------------------------------------------------
// out partials with fused tc-reduction: p2[kc][b][o]
__global__ __launch_bounds__(256) void k_out_part(const float* __restrict__ partial,
                                                  const float* __restrict__ Wo,
                                                  float* __restrict__ p2) {
  const int b = blockIdx.x;
  const int o = blockIdx.y * 256 + threadIdx.x;
  const int kc = blockIdx.z;
  __shared__ float cS[256];
  const int he0 = kc * 256;
  {
    float s = 0.f;
#pragma unroll
    for (int tc = 0; tc < TC_; ++tc)
      s += partial[((size_t)tc * B_ + b) * (H_ * E_) + he0 + threadIdx.x];
    cS[threadIdx.x] = s;
  }
  __syncthreads();
  float s = 0.f;
#pragma unroll 8
  for (int i = 0; i < 256; ++i) s += cS[i] * Wo[(size_t)(he0 + i) * O_ + o];
  p2[((size_t)kc * B_ + b) * O_ + o] = s;
}

__global__ __launch_bounds__(512) void k_out_fin(const float* __restrict__ p2,
                                                 const float* __restrict__ bo,
                                                 float* __restrict__ out) {
  const int b = blockIdx.x, o = threadIdx.x;
  float s = bo[o];
#pragma unroll
  for (int kc = 0; kc < 8; ++kc) s += p2[((size_t)kc * B_ + b) * O_ + o];
  out[b * O_ + o] = s;
}

// ---------------------------------------------------------------------------
extern "C" void kernel_launch(void* const* d_in, const int* in_sizes, int n_in,
                              void* d_out, int out_size, void* d_ws, size_t ws_size,
                              hipStream_t stream) {
  (void)in_sizes; (void)n_in; (void)out_size; (void)ws_size;
  const float* enc      = (const float*)d_in[0];
  // d_in[1] = enc_len : unused by the reference
  const float* dec_z    = (const float*)d_in[2];
  const float* att_prev = (const float*)d_in[3];
  const float* Wenc     = (const float*)d_in[4];
  const float* benc     = (const float*)d_in[5];
  const float* Wdec     = (const float*)d_in[6];
  const float* Watt     = (const float*)d_in[7];
  const float* conv_w   = (const float*)d_in[8];
  const float* gv       = (const float*)d_in[9];
  const float* Wo       = (const float*)d_in[10];
  const float* bo       = (const float*)d_in[11];

  float* out  = (float*)d_out;
  float* wout = out + B_ * O_;  // ws [H,B,T]

  char* wsb = (char*)d_ws;
  float*  e_buf   = (float*)(wsb);               // 1,024,000 B
  char*   convpad = wsb + 1024000;               // 8,192,000 B
  char*   wbs     = wsb + 9216000;               //   524,288 B
  char*   wattb   = wsb + 9740288;               //    16,384 B
  float*  addv4   = (float*)(wsb + 9756672);     //   131,072 B
  float2* msum    = (float2*)(wsb + 9887744);    //       512 B
  float*  partial = (float*)(wsb + 9888256);     // 6,553,600 B
  float*  p2      = (float*)(wsb + 16441856);    //   262,144 B

  hipLaunchKernelGGL(k_prep, dim3(257), dim3(256), 0, stream,
                     Wenc, Watt, dec_z, Wdec, benc, wbs, wattb, addv4);
  hipLaunchKernelGGL(k_conv, dim3(B_ * H_, 16), dim3(256), 0, stream, att_prev, conv_w, convpad);
  hipLaunchKernelGGL(k_fused_e_mfma, dim3(500), dim3(512), 0, stream,
                     enc, wbs, convpad, wattb, addv4, gv, e_buf);
  hipLaunchKernelGGL(k_msum, dim3(B_ * H_), dim3(256), 0, stream, e_buf, msum);
  hipLaunchKernelGGL(k_ctx, dim3(B_, TC_), dim3(128), 0, stream, enc, e_buf, msum, wout, partial);
  hipLaunchKernelGGL(k_out_part, dim3(B_, O_ / 256, 8), dim3(256), 0, stream, partial, Wo, p2);
  hipLaunchKernelGGL(k_out_fin, dim3(B_), dim3(512), 0, stream, p2, bo, out);
}

// Round 4
// 148.475 us; speedup vs baseline: 3.9725x; 3.9725x over previous
//
#include <hip/hip_runtime.h>
#include <hip/hip_bf16.h>

#define H_ 4
#define B_ 16
#define T_ 4000
#define E_ 512
#define D_ 512
#define A_ 128
#define C_ 10
#define K_ 101
#define O_ 512
#define TC_ 50
#define CH_ (T_ / TC_)   // 80

typedef __attribute__((ext_vector_type(16))) float f32x16;
typedef __attribute__((ext_vector_type(8)))  short short8;

#define MFMA32(a, b, c) __builtin_amdgcn_mfma_f32_32x32x16_bf16(a, b, c, 0, 0, 0)

#define GLL16(gp, lp) __builtin_amdgcn_global_load_lds( \
    (const __attribute__((address_space(1))) unsigned int*)(gp), \
    (__attribute__((address_space(3))) unsigned int*)(lp), 16, 0, 0)

static __device__ __forceinline__ unsigned short f2bf(float x) {
  unsigned u = __float_as_uint(x);
  unsigned r = (u + 0x7FFFu + ((u >> 16) & 1u)) >> 16;
  return (unsigned short)r;
}
static __device__ __forceinline__ unsigned pk2(float a, float b) {
  return (unsigned)f2bf(a) | ((unsigned)f2bf(b) << 16);
}
// HW packed cvt (v_cvt_pk_bf16_f32), RNE — same rounding as f2bf
static __device__ __forceinline__ unsigned pkcvt(float a, float b) {
  __hip_bfloat162 h2 = __float22bfloat162_rn(make_float2(a, b));
  unsigned u; __builtin_memcpy(&u, &h2, 4); return u;
}
static __device__ __forceinline__ uint4 packbf8(float4 f0, float4 f1) {
  uint4 u;
  u.x = pkcvt(f0.x, f0.y); u.y = pkcvt(f0.z, f0.w);
  u.z = pkcvt(f1.x, f1.y); u.w = pkcvt(f1.z, f1.w);
  return u;
}
static __device__ __forceinline__ f32x16 zero16() {
  f32x16 z;
#pragma unroll
  for (int i = 0; i < 16; ++i) z[i] = 0.f;
  return z;
}
static __device__ __forceinline__ float tanh_fast(float x) {
  return 1.0f - 2.0f / (__expf(2.0f * x) + 1.0f);
}
// swizzled byte offset for 32-k-wide bf16 tiles packed as 2 rows per 128B line
static __device__ __forceinline__ int swz32(int r, int ksg) {
  return (r >> 1) * 128 + (((((r & 1) << 2) | ksg) ^ ((r >> 1) & 7)) << 4);
}
// swizzled byte offset for 64-elem-wide bf16 rows (128B per row)
static __device__ __forceinline__ int swzC(int r, int sl) {
  return r * 128 + ((sl ^ (r & 7)) << 4);
}

// ---------------------------------------------------------------------------
// k_prep: (a) wbs  = pre-swizzled bf16 Wenc [16 kt][512 n][32 k]  (512 KB)
//         (b) wattb = pre-swizzled bf16 padded Watt                (16 KB)
//         (c) addv4[p][b][h][a] = 4-way split-K partials of benc + dec_z@Wdec
__global__ __launch_bounds__(256) void k_prep(const float* __restrict__ Wenc,
                                              const float* __restrict__ Watt,
                                              const float* __restrict__ dec_z,
                                              const float* __restrict__ Wdec,
                                              const float* __restrict__ benc,
                                              char* __restrict__ wbs,
                                              char* __restrict__ wattb,
                                              float* __restrict__ addv4) {
  const int bid = blockIdx.x;
  const int tid = threadIdx.x;
  if (bid < 128) {
    const int c = bid * 256 + tid;          // 16B chunk index into wbs
    const int cc = c & 2047;
    const int kt = c >> 11;
    const int line = cc >> 3, sp = cc & 7;
    const int sraw = sp ^ (line & 7);
    const int n = line * 2 + (sraw >> 2);
    const int ksg = sraw & 3;
    const int h = n >> 7, a = n & 127;
    const int kb = kt * 32 + ksg * 8;
    uint4 u;
    u.x = pk2(Wenc[((size_t)h * E_ + kb + 0) * A_ + a], Wenc[((size_t)h * E_ + kb + 1) * A_ + a]);
    u.y = pk2(Wenc[((size_t)h * E_ + kb + 2) * A_ + a], Wenc[((size_t)h * E_ + kb + 3) * A_ + a]);
    u.z = pk2(Wenc[((size_t)h * E_ + kb + 4) * A_ + a], Wenc[((size_t)h * E_ + kb + 5) * A_ + a]);
    u.w = pk2(Wenc[((size_t)h * E_ + kb + 6) * A_ + a], Wenc[((size_t)h * E_ + kb + 7) * A_ + a]);
    ((uint4*)wbs)[c] = u;
  } else if (bid == 128) {
#pragma unroll
    for (int q = 0; q < 4; ++q) {
      const int cw = q * 256 + tid;         // 1024 chunks
      const int h = cw >> 8, cc = cw & 255;
      const int line = cc >> 3, sp = cc & 7;
      const int sraw = sp ^ (line & 7);
      const int a = line * 4 + (sraw >> 1);
      const int s = sraw & 1;
      unsigned short v[8];
#pragma unroll
      for (int j = 0; j < 8; ++j) {
        const int k = s * 8 + j;
        v[j] = (k < C_) ? f2bf(Watt[((size_t)h * C_ + k) * A_ + a]) : (unsigned short)0;
      }
      uint4 u;
      u.x = (unsigned)v[0] | ((unsigned)v[1] << 16);
      u.y = (unsigned)v[2] | ((unsigned)v[3] << 16);
      u.z = (unsigned)v[4] | ((unsigned)v[5] << 16);
      u.w = (unsigned)v[6] | ((unsigned)v[7] << 16);
      ((uint4*)wattb)[cw] = u;
    }
  } else {
    // addv split-K: blocks 129..256 -> idx 0..127 = (b, h, ks)
    const int idx = bid - 129;
    const int b = idx >> 3, h = (idx >> 1) & 3, ks = idx & 1;
    const int a = tid & 127, kh = tid >> 7;
    const int p = ks * 2 + kh;              // partial id 0..3
    const int d0 = p * 128;
    const float* z = dec_z + (size_t)b * D_ + d0;
    const float* w = Wdec + ((size_t)h * D_ + d0) * A_ + a;
    float s = (p == 0) ? benc[h * A_ + a] : 0.f;
#pragma unroll 8
    for (int d = 0; d < 128; ++d) s += z[d] * w[(size_t)d * A_];
    addv4[(((size_t)p * B_ + b) * H_ + h) * A_ + a] = s;
  }
}

// ---------------------------------------------------------------------------
// conv features, bf16, padded: convpad[row=b*T+t][h*16 + c], c in [0,16)
__global__ __launch_bounds__(256) void k_conv(const float* __restrict__ att_prev,
                                              const float* __restrict__ conv_w,
                                              char* __restrict__ convpad) {
  const int bh = blockIdx.x;
  const int b = bh / H_, h = bh % H_;
  const int t0 = blockIdx.y * 256;
  __shared__ float ap[256 + K_ - 1 + 3];
  __shared__ float cw[C_ * K_];
  const float* src = att_prev + ((size_t)h * B_ + b) * T_;
  for (int i = threadIdx.x; i < 256 + K_ - 1; i += 256) {
    int tt = t0 - (K_ / 2) + i;
    ap[i] = (tt >= 0 && tt < T_) ? src[tt] : 0.f;
  }
  for (int i = threadIdx.x; i < C_ * K_; i += 256) cw[i] = conv_w[(size_t)h * C_ * K_ + i];
  __syncthreads();
  const int t = t0 + threadIdx.x;
  if (t < T_) {
    float s[C_];
#pragma unroll
    for (int c = 0; c < C_; ++c) s[c] = 0.f;
    for (int k = 0; k < K_; ++k) {
      float apv = ap[threadIdx.x + k];
#pragma unroll
      for (int c = 0; c < C_; ++c) s[c] += cw[c * K_ + k] * apv;
    }
    uint4 u0, u1;
    u0.x = pk2(s[0], s[1]); u0.y = pk2(s[2], s[3]);
    u0.z = pk2(s[4], s[5]); u0.w = pk2(s[6], s[7]);
    u1.x = pk2(s[8], s[9]); u1.y = 0u; u1.z = 0u; u1.w = 0u;
    char* dst = convpad + (size_t)(b * T_ + t) * 128 + h * 32;
    *(uint4*)dst = u0;
    *(uint4*)(dst + 16) = u1;
  }
}

// ---------------------------------------------------------------------------
// Fused MFMA: e[b,h,t] = sum_a gv[h,a]*tanh( enc@Wenc + conv@Watt + addv )
// Block: 128 rows x 512 cols (8 waves: wm 0..1 x head 0..3), BK=32, 16 kt + conv
// NOTE: __launch_bounds__(512, 2) -> 256 unified VGPRs/wave. acc[2][4] f32x16
// = 128 regs + ~96 arch = ~224. (512,4) caps at 128 and SPILLS (round-3: 1.4GB
// scratch writes, 601us). Do not raise the min-waves arg.
__global__ __launch_bounds__(512, 2) void k_fused_e_mfma(
    const float* __restrict__ enc,
    const char*  __restrict__ wbs,
    const char*  __restrict__ convpad,
    const char*  __restrict__ wattb,
    const float* __restrict__ addv4,
    const float* __restrict__ gv,
    float* __restrict__ e_out) {
  __shared__ char smem[81920];
  const int ABUF0o = 0, ABUF1o = 8192, BBUF0o = 16384, BBUF1o = 49152;
  const int tid = threadIdx.x;
  const int wv = tid >> 6;
  const int wh = wv & 3;        // head
  const int wm = wv >> 2;       // M-half (rows wm*64 .. +63)
  const int lane = tid & 63;
  const int ln31 = lane & 31;
  const int hi = lane >> 5;
  const int m0 = blockIdx.x * 128;
  const unsigned b0 = (unsigned)m0 / 4000u;
  const unsigned b1 = (unsigned)(m0 + 127) / 4000u;

  f32x16 acc[2][4];
#pragma unroll
  for (int i = 0; i < 2; ++i)
#pragma unroll
    for (int j = 0; j < 4; ++j) acc[i][j] = zero16();

  // staging geometry
  const int srow = tid >> 2, sksg = tid & 3;     // A: 4 threads/row, 32B each
  const int stA = swz32(srow, sksg);
  const float* encRow = enc + (size_t)(m0 + srow) * E_ + sksg * 8;
  const int wbase = wv * 1024;
  const int lof = lane * 16;

  // ---- prologue: stage K-tile 0
  {
    float4 f0 = ((const float4*)encRow)[0];
    float4 f1 = ((const float4*)encRow)[1];
    *(uint4*)(smem + ABUF0o + stA) = packbf8(f0, f1);
#pragma unroll
    for (int it = 0; it < 4; ++it)
      GLL16(wbs + (size_t)it * 8192 + wbase + lof, smem + BBUF0o + it * 8192 + wbase);
  }
  __syncthreads();

  for (int kt = 0; kt < 16; ++kt) {
    const int cur = kt & 1;
    const char* Ab = smem + (cur ? ABUF1o : ABUF0o);
    const char* Bb = smem + (cur ? BBUF1o : BBUF0o);
    char* An = smem + (cur ? ABUF0o : ABUF1o);
    char* Bn = smem + (cur ? BBUF0o : BBUF1o);

    uint4 pk = {0, 0, 0, 0};
    uint4 rc0 = {0, 0, 0, 0}, rc1 = {0, 0, 0, 0};
    float av0s = 0.f, av1s = 0.f, gvv = 0.f;

    if (kt < 15) {
      const float* apk = encRow + (kt + 1) * 32;
      float4 f0 = ((const float4*)apk)[0];
      float4 f1 = ((const float4*)apk)[1];
      pk = packbf8(f0, f1);
#pragma unroll
      for (int it = 0; it < 4; ++it)
        GLL16(wbs + (size_t)(kt + 1) * 32768 + it * 8192 + wbase + lof,
              Bn + it * 8192 + wbase);
    } else {
      // conv A-tile (16KB, reg roundtrip), Watt (16KB via GLL), addv sums, gv
      rc0 = *(const uint4*)(convpad + (size_t)(m0 + (tid >> 3)) * 128 + (tid & 7) * 16);
      rc1 = *(const uint4*)(convpad + (size_t)(m0 + ((tid + 512) >> 3)) * 128 + (tid & 7) * 16);
#pragma unroll
      for (int it = 0; it < 2; ++it)
        GLL16(wattb + (size_t)it * 8192 + wbase + lof, Bn + 16384 + it * 8192 + wbase);
      av0s = addv4[b0 * 512 + tid]        + addv4[8192 + b0 * 512 + tid]
           + addv4[16384 + b0 * 512 + tid] + addv4[24576 + b0 * 512 + tid];
      av1s = addv4[b1 * 512 + tid]        + addv4[8192 + b1 * 512 + tid]
           + addv4[16384 + b1 * 512 + tid] + addv4[24576 + b1 * 512 + tid];
      gvv = gv[tid];
    }

    // ---- compute on current buffers
#pragma unroll
    for (int kc = 0; kc < 2; ++kc) {
      const int ksg = kc * 2 + hi;
      short8 a0 = *(const short8*)(Ab + swz32(wm * 64 + ln31, ksg));
      short8 a1 = *(const short8*)(Ab + swz32(wm * 64 + 32 + ln31, ksg));
#pragma unroll
      for (int ni = 0; ni < 4; ++ni) {
        const int n = wh * 128 + ni * 32 + ln31;
        short8 bfr = *(const short8*)(Bb + swz32(n, ksg));
        acc[0][ni] = MFMA32(a0, bfr, acc[0][ni]);
        acc[1][ni] = MFMA32(a1, bfr, acc[1][ni]);
      }
    }

    if (kt < 15) {
      *(uint4*)(An + stA) = pk;
    } else {
      *(uint4*)(Bn + swzC(tid >> 3, tid & 7)) = rc0;
      *(uint4*)(Bn + swzC((tid + 512) >> 3, tid & 7)) = rc1;
      ((float*)An)[tid] = av0s;
      ((float*)An)[512 + tid] = av1s;
      ((float*)An)[1024 + tid] = gvv;
    }
    __syncthreads();
  }

  // ---- conv MFMA step (K=16): A = conv features, B = Watt
  {
    const char* AconvL = smem + BBUF0o;
    const char* WattL  = smem + BBUF0o + 16384;
    const int sl = wh * 2 + hi;
    short8 ac0 = *(const short8*)(AconvL + swzC(wm * 64 + ln31, sl));
    short8 ac1 = *(const short8*)(AconvL + swzC(wm * 64 + 32 + ln31, sl));
#pragma unroll
    for (int ni = 0; ni < 4; ++ni) {
      const int a = ni * 32 + ln31;
      short8 wf = *(const short8*)(WattL + wh * 4096 + (a >> 2) * 128 +
                                   (((((a & 3) << 1) | hi) ^ ((a >> 2) & 7)) << 4));
      acc[0][ni] = MFMA32(ac0, wf, acc[0][ni]);
      acc[1][ni] = MFMA32(ac1, wf, acc[1][ni]);
    }
  }

  // ---- epilogue
  {
    const float* An_f = (const float*)(smem + ABUF0o);
    float av0[4], av1[4], gvr[4];
#pragma unroll
    for (int ni = 0; ni < 4; ++ni) {
      const int a = wh * 128 + ni * 32 + ln31;
      av0[ni] = An_f[a];
      av1[ni] = An_f[512 + a];
      gvr[ni] = An_f[1024 + a];
    }
#pragma unroll
    for (int mi = 0; mi < 2; ++mi) {
#pragma unroll
      for (int reg = 0; reg < 16; ++reg) {
        const int rl = wm * 64 + mi * 32 + (reg & 3) + ((reg >> 2) << 3) + (hi << 2);
        const unsigned brow = (unsigned)(m0 + rl);
        const unsigned bb = brow / 4000u;
        const unsigned tt = brow - bb * 4000u;
        const int sel = (bb != b0);
        float rs = 0.f;
#pragma unroll
        for (int ni = 0; ni < 4; ++ni) {
          float s = acc[mi][ni][reg] + (sel ? av1[ni] : av0[ni]);
          rs += gvr[ni] * tanh_fast(s);
        }
        rs += __shfl_xor(rs, 1);
        rs += __shfl_xor(rs, 2);
        rs += __shfl_xor(rs, 4);
        rs += __shfl_xor(rs, 8);
        rs += __shfl_xor(rs, 16);
        if (ln31 == 0) e_out[((size_t)bb * H_ + wh) * T_ + tt] = rs;
      }
    }
  }
}

// ---------------------------------------------------------------------------
// per-(b,h) softmax stats: msum[bh] = (max, 1/sum)
__global__ __launch_bounds__(256) void k_msum(const float* __restrict__ e_in,
                                              float2* __restrict__ msum) {
  const int bh = blockIdx.x;
  const float* er = e_in + (size_t)bh * T_;
  __shared__ float red[256];
  const int tid = threadIdx.x;
  float m = -1e30f;
  for (int t = tid; t < T_; t += 256) m = fmaxf(m, er[t]);
  red[tid] = m;
  __syncthreads();
  for (int s = 128; s > 0; s >>= 1) {
    if (tid < s) red[tid] = fmaxf(red[tid], red[tid + s]);
    __syncthreads();
  }
  m = red[0];
  __syncthreads();
  float sum = 0.f;
  for (int t = tid; t < T_; t += 256) sum += __expf(er[t] - m);
  red[tid] = sum;
  __syncthreads();
  for (int s = 128; s > 0; s >>= 1) {
    if (tid < s) red[tid] += red[tid + s];
    __syncthreads();
  }
  if (tid == 0) msum[bh] = make_float2(m, 1.0f / red[0]);
}

// ---------------------------------------------------------------------------
// ctx + inline softmax: computes w = exp(e-m)/sum, writes ws output AND
// context partials partial[tc][b][h][E] for its 80-row chunk. float4 enc loads.
__global__ __launch_bounds__(128) void k_ctx(const float* __restrict__ enc,
                                             const float* __restrict__ e_in,
                                             const float2* __restrict__ msum,
                                             float* __restrict__ wout,
                                             float* __restrict__ partial) {
  const int b = blockIdx.x, tc = blockIdx.y;
  const int t0 = tc * CH_;
  const int tid = threadIdx.x;
  __shared__ float wls[H_ * CH_];
  for (int i = tid; i < H_ * CH_; i += 128) {
    const int h = i / CH_, tt = i - h * CH_;
    const float2 ms = msum[b * H_ + h];
    const float w = __expf(e_in[((size_t)b * H_ + h) * T_ + t0 + tt] - ms.x) * ms.y;
    wls[i] = w;
    wout[((size_t)h * B_ + b) * T_ + t0 + tt] = w;
  }
  __syncthreads();
  float4 a0 = {0,0,0,0}, a1 = {0,0,0,0}, a2 = {0,0,0,0}, a3 = {0,0,0,0};
  const float4* enc4 = (const float4*)enc;
  const size_t ebase = ((size_t)b * T_ + t0) * 128 + tid;   // float4 units, E/4=128
#pragma unroll 4
  for (int tt = 0; tt < CH_; ++tt) {
    const float4 x = enc4[ebase + (size_t)tt * 128];
    const float w0 = wls[tt], w1 = wls[CH_ + tt], w2 = wls[2 * CH_ + tt], w3 = wls[3 * CH_ + tt];
    a0.x += w0 * x.x; a0.y += w0 * x.y; a0.z += w0 * x.z; a0.w += w0 * x.w;
    a1.x += w1 * x.x; a1.y += w1 * x.y; a1.z += w1 * x.z; a1.w += w1 * x.w;
    a2.x += w2 * x.x; a2.y += w2 * x.y; a2.z += w2 * x.z; a2.w += w2 * x.w;
    a3.x += w3 * x.x; a3.y += w3 * x.y; a3.z += w3 * x.z; a3.w += w3 * x.w;
  }
  float4* p4 = (float4*)partial;
  const size_t pbase = (((size_t)tc * B_ + b) * H_) * 128 + tid;
  p4[pbase] = a0;
  p4[pbase + 128] = a1;
  p4[pbase + 256] = a2;
  p4[pbase + 384] = a3;
}

// ---------------------------------------------------------------------------
// out partials with fused tc-reduction: p2[kc][b][o]
__global__ __launch_bounds__(256) void k_out_part(const float* __restrict__ partial,
                                                  const float* __restrict__ Wo,
                                                  float* __restrict__ p2) {
  const int b = blockIdx.x;
  const int o = blockIdx.y * 256 + threadIdx.x;
  const int kc = blockIdx.z;
  __shared__ float cS[256];
  const int he0 = kc * 256;
  {
    float s = 0.f;
#pragma unroll
    for (int tc = 0; tc < TC_; ++tc)
      s += partial[((size_t)tc * B_ + b) * (H_ * E_) + he0 + threadIdx.x];
    cS[threadIdx.x] = s;
  }
  __syncthreads();
  float s = 0.f;
#pragma unroll 8
  for (int i = 0; i < 256; ++i) s += cS[i] * Wo[(size_t)(he0 + i) * O_ + o];
  p2[((size_t)kc * B_ + b) * O_ + o] = s;
}

__global__ __launch_bounds__(512) void k_out_fin(const float* __restrict__ p2,
                                                 const float* __restrict__ bo,
                                                 float* __restrict__ out) {
  const int b = blockIdx.x, o = threadIdx.x;
  float s = bo[o];
#pragma unroll
  for (int kc = 0; kc < 8; ++kc) s += p2[((size_t)kc * B_ + b) * O_ + o];
  out[b * O_ + o] = s;
}

// ---------------------------------------------------------------------------
extern "C" void kernel_launch(void* const* d_in, const int* in_sizes, int n_in,
                              void* d_out, int out_size, void* d_ws, size_t ws_size,
                              hipStream_t stream) {
  (void)in_sizes; (void)n_in; (void)out_size; (void)ws_size;
  const float* enc      = (const float*)d_in[0];
  // d_in[1] = enc_len : unused by the reference
  const float* dec_z    = (const float*)d_in[2];
  const float* att_prev = (const float*)d_in[3];
  const float* Wenc     = (const float*)d_in[4];
  const float* benc     = (const float*)d_in[5];
  const float* Wdec     = (const float*)d_in[6];
  const float* Watt     = (const float*)d_in[7];
  const float* conv_w   = (const float*)d_in[8];
  const float* gv       = (const float*)d_in[9];
  const float* Wo       = (const float*)d_in[10];
  const float* bo       = (const float*)d_in[11];

  float* out  = (float*)d_out;
  float* wout = out + B_ * O_;  // ws [H,B,T]

  char* wsb = (char*)d_ws;
  float*  e_buf   = (float*)(wsb);               // 1,024,000 B
  char*   convpad = wsb + 1024000;               // 8,192,000 B
  char*   wbs     = wsb + 9216000;               //   524,288 B
  char*   wattb   = wsb + 9740288;               //    16,384 B
  float*  addv4   = (float*)(wsb + 9756672);     //   131,072 B
  float2* msum    = (float2*)(wsb + 9887744);    //       512 B
  float*  partial = (float*)(wsb + 9888256);     // 6,553,600 B
  float*  p2      = (float*)(wsb + 16441856);    //   262,144 B

  hipLaunchKernelGGL(k_prep, dim3(257), dim3(256), 0, stream,
                     Wenc, Watt, dec_z, Wdec, benc, wbs, wattb, addv4);
  hipLaunchKernelGGL(k_conv, dim3(B_ * H_, 16), dim3(256), 0, stream, att_prev, conv_w, convpad);
  hipLaunchKernelGGL(k_fused_e_mfma, dim3(500), dim3(512), 0, stream,
                     enc, wbs, convpad, wattb, addv4, gv, e_buf);
  hipLaunchKernelGGL(k_msum, dim3(B_ * H_), dim3(256), 0, stream, e_buf, msum);
  hipLaunchKernelGGL(k_ctx, dim3(B_, TC_), dim3(128), 0, stream, enc, e_buf, msum, wout, partial);
  hipLaunchKernelGGL(k_out_part, dim3(B_, O_ / 256, 8), dim3(256), 0, stream, partial, Wo, p2);
  hipLaunchKernelGGL(k_out_fin, dim3(B_), dim3(512), 0, stream, p2, bo, out);
}

// Round 5
// 145.500 us; speedup vs baseline: 4.0538x; 1.0204x over previous
//
#include <hip/hip_runtime.h>
#include <hip/hip_bf16.h>

#define H_ 4
#define B_ 16
#define T_ 4000
#define E_ 512
#define D_ 512
#define A_ 128
#define C_ 10
#define K_ 101
#define O_ 512
#define TC_ 50
#define CH_ (T_ / TC_)   // 80

typedef __attribute__((ext_vector_type(16))) float f32x16;
typedef __attribute__((ext_vector_type(8)))  short short8;

#define MFMA32(a, b, c) __builtin_amdgcn_mfma_f32_32x32x16_bf16(a, b, c, 0, 0, 0)

#define GLL16(gp, lp) __builtin_amdgcn_global_load_lds( \
    (const __attribute__((address_space(1))) unsigned int*)(gp), \
    (__attribute__((address_space(3))) unsigned int*)(lp), 16, 0, 0)

static __device__ __forceinline__ unsigned short f2bf(float x) {
  unsigned u = __float_as_uint(x);
  unsigned r = (u + 0x7FFFu + ((u >> 16) & 1u)) >> 16;
  return (unsigned short)r;
}
static __device__ __forceinline__ unsigned pk2(float a, float b) {
  return (unsigned)f2bf(a) | ((unsigned)f2bf(b) << 16);
}
// HW packed cvt (v_cvt_pk_bf16_f32), RNE — same rounding as f2bf
static __device__ __forceinline__ unsigned pkcvt(float a, float b) {
  __hip_bfloat162 h2 = __float22bfloat162_rn(make_float2(a, b));
  unsigned u; __builtin_memcpy(&u, &h2, 4); return u;
}
static __device__ __forceinline__ uint4 packbf8(float4 f0, float4 f1) {
  uint4 u;
  u.x = pkcvt(f0.x, f0.y); u.y = pkcvt(f0.z, f0.w);
  u.z = pkcvt(f1.x, f1.y); u.w = pkcvt(f1.z, f1.w);
  return u;
}
static __device__ __forceinline__ f32x16 zero16() {
  f32x16 z;
#pragma unroll
  for (int i = 0; i < 16; ++i) z[i] = 0.f;
  return z;
}
static __device__ __forceinline__ float tanh_fast(float x) {
  return 1.0f - 2.0f / (__expf(2.0f * x) + 1.0f);
}
// swizzled byte offset for 32-k-wide bf16 tiles packed as 2 rows per 128B line
static __device__ __forceinline__ int swz32(int r, int ksg) {
  return (r >> 1) * 128 + (((((r & 1) << 2) | ksg) ^ ((r >> 1) & 7)) << 4);
}
// swizzled byte offset for 64-elem-wide bf16 rows (128B per row)
static __device__ __forceinline__ int swzC(int r, int sl) {
  return r * 128 + ((sl ^ (r & 7)) << 4);
}

// ---------------------------------------------------------------------------
// k_prep: (a) wbs  = pre-swizzled bf16 Wenc [16 kt][512 n][32 k]  (512 KB)
//         (b) wattb = pre-swizzled bf16 padded Watt                (16 KB)
//         (c) addv4[p][b][h][a] = 4-way split-K partials of benc + dec_z@Wdec
__global__ __launch_bounds__(256) void k_prep(const float* __restrict__ Wenc,
                                              const float* __restrict__ Watt,
                                              const float* __restrict__ dec_z,
                                              const float* __restrict__ Wdec,
                                              const float* __restrict__ benc,
                                              char* __restrict__ wbs,
                                              char* __restrict__ wattb,
                                              float* __restrict__ addv4) {
  const int bid = blockIdx.x;
  const int tid = threadIdx.x;
  if (bid < 128) {
    const int c = bid * 256 + tid;          // 16B chunk index into wbs
    const int cc = c & 2047;
    const int kt = c >> 11;
    const int line = cc >> 3, sp = cc & 7;
    const int sraw = sp ^ (line & 7);
    const int n = line * 2 + (sraw >> 2);
    const int ksg = sraw & 3;
    const int h = n >> 7, a = n & 127;
    const int kb = kt * 32 + ksg * 8;
    uint4 u;
    u.x = pk2(Wenc[((size_t)h * E_ + kb + 0) * A_ + a], Wenc[((size_t)h * E_ + kb + 1) * A_ + a]);
    u.y = pk2(Wenc[((size_t)h * E_ + kb + 2) * A_ + a], Wenc[((size_t)h * E_ + kb + 3) * A_ + a]);
    u.z = pk2(Wenc[((size_t)h * E_ + kb + 4) * A_ + a], Wenc[((size_t)h * E_ + kb + 5) * A_ + a]);
    u.w = pk2(Wenc[((size_t)h * E_ + kb + 6) * A_ + a], Wenc[((size_t)h * E_ + kb + 7) * A_ + a]);
    ((uint4*)wbs)[c] = u;
  } else if (bid == 128) {
#pragma unroll
    for (int q = 0; q < 4; ++q) {
      const int cw = q * 256 + tid;         // 1024 chunks
      const int h = cw >> 8, cc = cw & 255;
      const int line = cc >> 3, sp = cc & 7;
      const int sraw = sp ^ (line & 7);
      const int a = line * 4 + (sraw >> 1);
      const int s = sraw & 1;
      unsigned short v[8];
#pragma unroll
      for (int j = 0; j < 8; ++j) {
        const int k = s * 8 + j;
        v[j] = (k < C_) ? f2bf(Watt[((size_t)h * C_ + k) * A_ + a]) : (unsigned short)0;
      }
      uint4 u;
      u.x = (unsigned)v[0] | ((unsigned)v[1] << 16);
      u.y = (unsigned)v[2] | ((unsigned)v[3] << 16);
      u.z = (unsigned)v[4] | ((unsigned)v[5] << 16);
      u.w = (unsigned)v[6] | ((unsigned)v[7] << 16);
      ((uint4*)wattb)[cw] = u;
    }
  } else {
    // addv split-K: blocks 129..256 -> idx 0..127 = (b, h, ks)
    const int idx = bid - 129;
    const int b = idx >> 3, h = (idx >> 1) & 3, ks = idx & 1;
    const int a = tid & 127, kh = tid >> 7;
    const int p = ks * 2 + kh;              // partial id 0..3
    const int d0 = p * 128;
    const float* z = dec_z + (size_t)b * D_ + d0;
    const float* w = Wdec + ((size_t)h * D_ + d0) * A_ + a;
    float s = (p == 0) ? benc[h * A_ + a] : 0.f;
#pragma unroll 8
    for (int d = 0; d < 128; ++d) s += z[d] * w[(size_t)d * A_];
    addv4[(((size_t)p * B_ + b) * H_ + h) * A_ + a] = s;
  }
}

// ---------------------------------------------------------------------------
// conv features, bf16, padded: convpad[row=b*T+t][h*16 + c], c in [0,16)
__global__ __launch_bounds__(256) void k_conv(const float* __restrict__ att_prev,
                                              const float* __restrict__ conv_w,
                                              char* __restrict__ convpad) {
  const int bh = blockIdx.x;
  const int b = bh / H_, h = bh % H_;
  const int t0 = blockIdx.y * 256;
  __shared__ float ap[256 + K_ - 1 + 3];
  __shared__ float cw[C_ * K_];
  const float* src = att_prev + ((size_t)h * B_ + b) * T_;
  for (int i = threadIdx.x; i < 256 + K_ - 1; i += 256) {
    int tt = t0 - (K_ / 2) + i;
    ap[i] = (tt >= 0 && tt < T_) ? src[tt] : 0.f;
  }
  for (int i = threadIdx.x; i < C_ * K_; i += 256) cw[i] = conv_w[(size_t)h * C_ * K_ + i];
  __syncthreads();
  const int t = t0 + threadIdx.x;
  if (t < T_) {
    float s[C_];
#pragma unroll
    for (int c = 0; c < C_; ++c) s[c] = 0.f;
    for (int k = 0; k < K_; ++k) {
      float apv = ap[threadIdx.x + k];
#pragma unroll
      for (int c = 0; c < C_; ++c) s[c] += cw[c * K_ + k] * apv;
    }
    uint4 u0, u1;
    u0.x = pk2(s[0], s[1]); u0.y = pk2(s[2], s[3]);
    u0.z = pk2(s[4], s[5]); u0.w = pk2(s[6], s[7]);
    u1.x = pk2(s[8], s[9]); u1.y = 0u; u1.z = 0u; u1.w = 0u;
    char* dst = convpad + (size_t)(b * T_ + t) * 128 + h * 32;
    *(uint4*)dst = u0;
    *(uint4*)(dst + 16) = u1;
  }
}

// ---------------------------------------------------------------------------
// Fused MFMA: e[b,h,t] = sum_a gv[h,a]*tanh( enc@Wenc + conv@Watt + addv )
// Block: 128 rows x 512 cols (8 waves: wm 0..1 x head 0..3), BK=32, 16 kt + conv
// Sync structure (T3/T4): GLL16 B(kt+1) issued FIRST (oldest), enc A(kt+2)
// loads LAST (youngest, 2 ops); barrier = s_waitcnt vmcnt(2) + raw s_barrier,
// so the A loads stay in flight ACROSS the barrier (2-K-step latency window).
// NOTE: __launch_bounds__(512, 2) -> 256 unified VGPRs/wave. acc[2][4] f32x16
// = 128 regs; (512,4) SPILLS (round-3: 1.4GB scratch, 601us). Don't raise it.
__global__ __launch_bounds__(512, 2) void k_fused_e_mfma(
    const float* __restrict__ enc,
    const char*  __restrict__ wbs,
    const char*  __restrict__ convpad,
    const char*  __restrict__ wattb,
    const float* __restrict__ addv4,
    const float* __restrict__ gv,
    float* __restrict__ e_out) {
  __shared__ char smem[81920];
  const int ABUF0o = 0, ABUF1o = 8192, BBUF0o = 16384, BBUF1o = 49152;
  const int tid = threadIdx.x;
  const int wv = tid >> 6;
  const int wh = wv & 3;        // head
  const int wm = wv >> 2;       // M-half (rows wm*64 .. +63)
  const int lane = tid & 63;
  const int ln31 = lane & 31;
  const int hi = lane >> 5;
  const int m0 = blockIdx.x * 128;
  const unsigned b0 = (unsigned)m0 / 4000u;
  const unsigned b1 = (unsigned)(m0 + 127) / 4000u;

  f32x16 acc[2][4];
#pragma unroll
  for (int i = 0; i < 2; ++i)
#pragma unroll
    for (int j = 0; j < 4; ++j) acc[i][j] = zero16();

  // staging geometry
  const int srow = tid >> 2, sksg = tid & 3;     // A: 4 threads/row, 32B each
  const int stA = swz32(srow, sksg);
  const float* encRow = enc + (size_t)(m0 + srow) * E_ + sksg * 8;
  const int wbase = wv * 1024;
  const int lof = lane * 16;

  // ---- prologue: GLL16 B0 first (oldest), then A0+A1 enc loads; pack+write
  // A0; barrier leaves A1's 2 loads in flight (vmcnt(2)).
#pragma unroll
  for (int it = 0; it < 4; ++it)
    GLL16(wbs + (size_t)it * 8192 + wbase + lof, smem + BBUF0o + it * 8192 + wbase);
  __builtin_amdgcn_sched_barrier(0);
  float4 cF0 = ((const float4*)encRow)[0];
  float4 cF1 = ((const float4*)encRow)[1];
  float4 nF0 = ((const float4*)(encRow + 32))[0];
  float4 nF1 = ((const float4*)(encRow + 32))[1];
  *(uint4*)(smem + ABUF0o + stA) = packbf8(cF0, cF1);   // auto vmcnt(2) for cF
  cF0 = nF0; cF1 = nF1;
  asm volatile("s_waitcnt vmcnt(2) lgkmcnt(0)" ::: "memory");
  __builtin_amdgcn_sched_barrier(0);
  __builtin_amdgcn_s_barrier();

  uint4 rc0 = {0, 0, 0, 0}, rc1 = {0, 0, 0, 0};
  float av0s = 0.f, av1s = 0.f, gvv = 0.f;

#pragma unroll
  for (int kt = 0; kt < 16; ++kt) {
    const int cur = kt & 1;
    const char* Ab = smem + (cur ? ABUF1o : ABUF0o);
    const char* Bb = smem + (cur ? BBUF1o : BBUF0o);
    char* An = smem + (cur ? ABUF0o : ABUF1o);
    char* Bn = smem + (cur ? BBUF0o : BBUF1o);

    // (1) next B-tile via GLL16 — issued first: oldest VMEM of this iteration
    if (kt < 15) {
#pragma unroll
      for (int it = 0; it < 4; ++it)
        GLL16(wbs + (size_t)(kt + 1) * 32768 + it * 8192 + wbase + lof,
              Bn + it * 8192 + wbase);
    } else {
#pragma unroll
      for (int it = 0; it < 2; ++it)
        GLL16(wattb + (size_t)it * 8192 + wbase + lof, Bn + 16384 + it * 8192 + wbase);
    }
    __builtin_amdgcn_sched_barrier(0);

    // (2) A(kt+2) enc loads — youngest VMEM; stay in flight across the barrier
    if (kt < 14) {
      nF0 = ((const float4*)(encRow + (kt + 2) * 32))[0];
      nF1 = ((const float4*)(encRow + (kt + 2) * 32))[1];
    }
    if (kt == 15) {
      // conv A-tile regs + addv sums + gv (one-time epilogue staging)
      rc0 = *(const uint4*)(convpad + (size_t)(m0 + (tid >> 3)) * 128 + (tid & 7) * 16);
      rc1 = *(const uint4*)(convpad + (size_t)(m0 + ((tid + 512) >> 3)) * 128 + (tid & 7) * 16);
      av0s = addv4[b0 * 512 + tid]        + addv4[8192 + b0 * 512 + tid]
           + addv4[16384 + b0 * 512 + tid] + addv4[24576 + b0 * 512 + tid];
      av1s = addv4[b1 * 512 + tid]        + addv4[8192 + b1 * 512 + tid]
           + addv4[16384 + b1 * 512 + tid] + addv4[24576 + b1 * 512 + tid];
      gvv = gv[tid];
    }

    // (3) MFMA on current buffers
#pragma unroll
    for (int kc = 0; kc < 2; ++kc) {
      const int ksg = kc * 2 + hi;
      short8 a0 = *(const short8*)(Ab + swz32(wm * 64 + ln31, ksg));
      short8 a1 = *(const short8*)(Ab + swz32(wm * 64 + 32 + ln31, ksg));
#pragma unroll
      for (int ni = 0; ni < 4; ++ni) {
        const int n = wh * 128 + ni * 32 + ln31;
        short8 bfr = *(const short8*)(Bb + swz32(n, ksg));
        acc[0][ni] = MFMA32(a0, bfr, acc[0][ni]);
        acc[1][ni] = MFMA32(a1, bfr, acc[1][ni]);
      }
    }

    // (4) pack+write A(kt+1) (auto-wait vmcnt(6) covers only its own loads)
    if (kt < 15) {
      *(uint4*)(An + stA) = packbf8(cF0, cF1);
      cF0 = nF0; cF1 = nF1;
    } else {
      *(uint4*)(Bn + swzC(tid >> 3, tid & 7)) = rc0;
      *(uint4*)(Bn + swzC((tid + 512) >> 3, tid & 7)) = rc1;
      ((float*)An)[tid] = av0s;
      ((float*)An)[512 + tid] = av1s;
      ((float*)An)[1024 + tid] = gvv;
    }

    // (5) counted-vmcnt barrier: keep the 2 A(kt+2) loads in flight
    if (kt < 14) {
      asm volatile("s_waitcnt vmcnt(2) lgkmcnt(0)" ::: "memory");
    } else {
      asm volatile("s_waitcnt vmcnt(0) lgkmcnt(0)" ::: "memory");
    }
    __builtin_amdgcn_sched_barrier(0);
    __builtin_amdgcn_s_barrier();
  }

  // ---- conv MFMA step (K=16): A = conv features, B = Watt
  {
    const char* AconvL = smem + BBUF0o;
    const char* WattL  = smem + BBUF0o + 16384;
    const int sl = wh * 2 + hi;
    short8 ac0 = *(const short8*)(AconvL + swzC(wm * 64 + ln31, sl));
    short8 ac1 = *(const short8*)(AconvL + swzC(wm * 64 + 32 + ln31, sl));
#pragma unroll
    for (int ni = 0; ni < 4; ++ni) {
      const int a = ni * 32 + ln31;
      short8 wf = *(const short8*)(WattL + wh * 4096 + (a >> 2) * 128 +
                                   (((((a & 3) << 1) | hi) ^ ((a >> 2) & 7)) << 4));
      acc[0][ni] = MFMA32(ac0, wf, acc[0][ni]);
      acc[1][ni] = MFMA32(ac1, wf, acc[1][ni]);
    }
  }

  // ---- epilogue
  {
    const float* An_f = (const float*)(smem + ABUF0o);
    float av0[4], av1[4], gvr[4];
#pragma unroll
    for (int ni = 0; ni < 4; ++ni) {
      const int a = wh * 128 + ni * 32 + ln31;
      av0[ni] = An_f[a];
      av1[ni] = An_f[512 + a];
      gvr[ni] = An_f[1024 + a];
    }
#pragma unroll
    for (int mi = 0; mi < 2; ++mi) {
#pragma unroll
      for (int reg = 0; reg < 16; ++reg) {
        const int rl = wm * 64 + mi * 32 + (reg & 3) + ((reg >> 2) << 3) + (hi << 2);
        const unsigned brow = (unsigned)(m0 + rl);
        const unsigned bb = brow / 4000u;
        const unsigned tt = brow - bb * 4000u;
        const int sel = (bb != b0);
        float rs = 0.f;
#pragma unroll
        for (int ni = 0; ni < 4; ++ni) {
          float s = acc[mi][ni][reg] + (sel ? av1[ni] : av0[ni]);
          rs += gvr[ni] * tanh_fast(s);
        }
        rs += __shfl_xor(rs, 1);
        rs += __shfl_xor(rs, 2);
        rs += __shfl_xor(rs, 4);
        rs += __shfl_xor(rs, 8);
        rs += __shfl_xor(rs, 16);
        if (ln31 == 0) e_out[((size_t)bb * H_ + wh) * T_ + tt] = rs;
      }
    }
  }
}

// ---------------------------------------------------------------------------
// per-(b,h) softmax stats: msum[bh] = (max, 1/sum)
__global__ __launch_bounds__(256) void k_msum(const float* __restrict__ e_in,
                                              float2* __restrict__ msum) {
  const int bh = blockIdx.x;
  const float* er = e_in + (size_t)bh * T_;
  __shared__ float red[256];
  const int tid = threadIdx.x;
  float m = -1e30f;
  for (int t = tid; t < T_; t += 256) m = fmaxf(m, er[t]);
  red[tid] = m;
  __syncthreads();
  for (int s = 128; s > 0; s >>= 1) {
    if (tid < s) red[tid] = fmaxf(red[tid], red[tid + s]);
    __syncthreads();
  }
  m = red[0];
  __syncthreads();
  float sum = 0.f;
  for (int t = tid; t < T_; t += 256) sum += __expf(er[t] - m);
  red[tid] = sum;
  __syncthreads();
  for (int s = 128; s > 0; s >>= 1) {
    if (tid < s) red[tid] += red[tid + s];
    __syncthreads();
  }
  if (tid == 0) msum[bh] = make_float2(m, 1.0f / red[0]);
}

// ---------------------------------------------------------------------------
// ctx + inline softmax: computes w = exp(e-m)/sum, writes ws output AND
// context partials partial[tc][b][h][E] for its 80-row chunk. float4 enc loads.
__global__ __launch_bounds__(128) void k_ctx(const float* __restrict__ enc,
                                             const float* __restrict__ e_in,
                                             const float2* __restrict__ msum,
                                             float* __restrict__ wout,
                                             float* __restrict__ partial) {
  const int b = blockIdx.x, tc = blockIdx.y;
  const int t0 = tc * CH_;
  const int tid = threadIdx.x;
  __shared__ float wls[H_ * CH_];
  for (int i = tid; i < H_ * CH_; i += 128) {
    const int h = i / CH_, tt = i - h * CH_;
    const float2 ms = msum[b * H_ + h];
    const float w = __expf(e_in[((size_t)b * H_ + h) * T_ + t0 + tt] - ms.x) * ms.y;
    wls[i] = w;
    wout[((size_t)h * B_ + b) * T_ + t0 + tt] = w;
  }
  __syncthreads();
  float4 a0 = {0,0,0,0}, a1 = {0,0,0,0}, a2 = {0,0,0,0}, a3 = {0,0,0,0};
  const float4* enc4 = (const float4*)enc;
  const size_t ebase = ((size_t)b * T_ + t0) * 128 + tid;   // float4 units, E/4=128
#pragma unroll 8
  for (int tt = 0; tt < CH_; ++tt) {
    const float4 x = enc4[ebase + (size_t)tt * 128];
    const float w0 = wls[tt], w1 = wls[CH_ + tt], w2 = wls[2 * CH_ + tt], w3 = wls[3 * CH_ + tt];
    a0.x += w0 * x.x; a0.y += w0 * x.y; a0.z += w0 * x.z; a0.w += w0 * x.w;
    a1.x += w1 * x.x; a1.y += w1 * x.y; a1.z += w1 * x.z; a1.w += w1 * x.w;
    a2.x += w2 * x.x; a2.y += w2 * x.y; a2.z += w2 * x.z; a2.w += w2 * x.w;
    a3.x += w3 * x.x; a3.y += w3 * x.y; a3.z += w3 * x.z; a3.w += w3 * x.w;
  }
  float4* p4 = (float4*)partial;
  const size_t pbase = (((size_t)tc * B_ + b) * H_) * 128 + tid;
  p4[pbase] = a0;
  p4[pbase + 128] = a1;
  p4[pbase + 256] = a2;
  p4[pbase + 384] = a3;
}

// ---------------------------------------------------------------------------
// out partials with fused tc-reduction: p2[kc][b][o]
__global__ __launch_bounds__(256) void k_out_part(const float* __restrict__ partial,
                                                  const float* __restrict__ Wo,
                                                  float* __restrict__ p2) {
  const int b = blockIdx.x;
  const int o = blockIdx.y * 256 + threadIdx.x;
  const int kc = blockIdx.z;
  __shared__ float cS[256];
  const int he0 = kc * 256;
  {
    float s = 0.f;
#pragma unroll
    for (int tc = 0; tc < TC_; ++tc)
      s += partial[((size_t)tc * B_ + b) * (H_ * E_) + he0 + threadIdx.x];
    cS[threadIdx.x] = s;
  }
  __syncthreads();
  float s = 0.f;
#pragma unroll 8
  for (int i = 0; i < 256; ++i) s += cS[i] * Wo[(size_t)(he0 + i) * O_ + o];
  p2[((size_t)kc * B_ + b) * O_ + o] = s;
}

__global__ __launch_bounds__(512) void k_out_fin(const float* __restrict__ p2,
                                                 const float* __restrict__ bo,
                                                 float* __restrict__ out) {
  const int b = blockIdx.x, o = threadIdx.x;
  float s = bo[o];
#pragma unroll
  for (int kc = 0; kc < 8; ++kc) s += p2[((size_t)kc * B_ + b) * O_ + o];
  out[b * O_ + o] = s;
}

// ---------------------------------------------------------------------------
extern "C" void kernel_launch(void* const* d_in, const int* in_sizes, int n_in,
                              void* d_out, int out_size, void* d_ws, size_t ws_size,
                              hipStream_t stream) {
  (void)in_sizes; (void)n_in; (void)out_size; (void)ws_size;
  const float* enc      = (const float*)d_in[0];
  // d_in[1] = enc_len : unused by the reference
  const float* dec_z    = (const float*)d_in[2];
  const float* att_prev = (const float*)d_in[3];
  const float* Wenc     = (const float*)d_in[4];
  const float* benc     = (const float*)d_in[5];
  const float* Wdec     = (const float*)d_in[6];
  const float* Watt     = (const float*)d_in[7];
  const float* conv_w   = (const float*)d_in[8];
  const float* gv       = (const float*)d_in[9];
  const float* Wo       = (const float*)d_in[10];
  const float* bo       = (const float*)d_in[11];

  float* out  = (float*)d_out;
  float* wout = out + B_ * O_;  // ws [H,B,T]

  char* wsb = (char*)d_ws;
  float*  e_buf   = (float*)(wsb);               // 1,024,000 B
  char*   convpad = wsb + 1024000;               // 8,192,000 B
  char*   wbs     = wsb + 9216000;               //   524,288 B
  char*   wattb   = wsb + 9740288;               //    16,384 B
  float*  addv4   = (float*)(wsb + 9756672);     //   131,072 B
  float2* msum    = (float2*)(wsb + 9887744);    //       512 B
  float*  partial = (float*)(wsb + 9888256);     // 6,553,600 B
  float*  p2      = (float*)(wsb + 16441856);    //   262,144 B

  hipLaunchKernelGGL(k_prep, dim3(257), dim3(256), 0, stream,
                     Wenc, Watt, dec_z, Wdec, benc, wbs, wattb, addv4);
  hipLaunchKernelGGL(k_conv, dim3(B_ * H_, 16), dim3(256), 0, stream, att_prev, conv_w, convpad);
  hipLaunchKernelGGL(k_fused_e_mfma, dim3(500), dim3(512), 0, stream,
                     enc, wbs, convpad, wattb, addv4, gv, e_buf);
  hipLaunchKernelGGL(k_msum, dim3(B_ * H_), dim3(256), 0, stream, e_buf, msum);
  hipLaunchKernelGGL(k_ctx, dim3(B_, TC_), dim3(128), 0, stream, enc, e_buf, msum, wout, partial);
  hipLaunchKernelGGL(k_out_part, dim3(B_, O_ / 256, 8), dim3(256), 0, stream, partial, Wo, p2);
  hipLaunchKernelGGL(k_out_fin, dim3(B_), dim3(512), 0, stream, p2, bo, out);
}

// Round 6
// 143.394 us; speedup vs baseline: 4.1133x; 1.0147x over previous
//
#include <hip/hip_runtime.h>
#include <hip/hip_bf16.h>

#define H_ 4
#define B_ 16
#define T_ 4000
#define E_ 512
#define D_ 512
#define A_ 128
#define C_ 10
#define K_ 101
#define O_ 512
#define TC_ 50
#define CH_ (T_ / TC_)   // 80

typedef __attribute__((ext_vector_type(16))) float f32x16;
typedef __attribute__((ext_vector_type(8)))  short short8;

#define MFMA32(a, b, c) __builtin_amdgcn_mfma_f32_32x32x16_bf16(a, b, c, 0, 0, 0)

#define GLL16(gp, lp) __builtin_amdgcn_global_load_lds( \
    (const __attribute__((address_space(1))) unsigned int*)(gp), \
    (__attribute__((address_space(3))) unsigned int*)(lp), 16, 0, 0)

static __device__ __forceinline__ unsigned short f2bf(float x) {
  unsigned u = __float_as_uint(x);
  unsigned r = (u + 0x7FFFu + ((u >> 16) & 1u)) >> 16;
  return (unsigned short)r;
}
static __device__ __forceinline__ unsigned pk2(float a, float b) {
  return (unsigned)f2bf(a) | ((unsigned)f2bf(b) << 16);
}
// single-instruction packed f32x2 -> bf16x2 (RNE), lo=src0 hi=src1
static __device__ __forceinline__ unsigned cvtpk(float lo, float hi) {
  unsigned r;
  asm("v_cvt_pk_bf16_f32 %0, %1, %2" : "=v"(r) : "v"(lo), "v"(hi));
  return r;
}
static __device__ __forceinline__ uint4 packbf8(float4 f0, float4 f1) {
  uint4 u;
  u.x = cvtpk(f0.x, f0.y); u.y = cvtpk(f0.z, f0.w);
  u.z = cvtpk(f1.x, f1.y); u.w = cvtpk(f1.z, f1.w);
  return u;
}
static __device__ __forceinline__ f32x16 zero16() {
  f32x16 z;
#pragma unroll
  for (int i = 0; i < 16; ++i) z[i] = 0.f;
  return z;
}
static __device__ __forceinline__ float tanh_fast(float x) {
  return 1.0f - 2.0f / (__expf(2.0f * x) + 1.0f);
}
// swizzled byte offset for 32-k-wide bf16 tiles packed as 2 rows per 128B line
static __device__ __forceinline__ int swz32(int r, int ksg) {
  return (r >> 1) * 128 + (((((r & 1) << 2) | ksg) ^ ((r >> 1) & 7)) << 4);
}
// swizzled byte offset for 64-elem-wide bf16 rows (128B per row)
static __device__ __forceinline__ int swzC(int r, int sl) {
  return r * 128 + ((sl ^ (r & 7)) << 4);
}

// ---------------------------------------------------------------------------
__global__ __launch_bounds__(256) void k_prep(const float* __restrict__ Wenc,
                                              const float* __restrict__ Watt,
                                              const float* __restrict__ dec_z,
                                              const float* __restrict__ Wdec,
                                              const float* __restrict__ benc,
                                              char* __restrict__ wbs,
                                              char* __restrict__ wattb,
                                              float* __restrict__ addv4) {
  const int bid = blockIdx.x;
  const int tid = threadIdx.x;
  if (bid < 128) {
    const int c = bid * 256 + tid;          // 16B chunk index into wbs
    const int cc = c & 2047;
    const int kt = c >> 11;
    const int line = cc >> 3, sp = cc & 7;
    const int sraw = sp ^ (line & 7);
    const int n = line * 2 + (sraw >> 2);
    const int ksg = sraw & 3;
    const int h = n >> 7, a = n & 127;
    const int kb = kt * 32 + ksg * 8;
    uint4 u;
    u.x = pk2(Wenc[((size_t)h * E_ + kb + 0) * A_ + a], Wenc[((size_t)h * E_ + kb + 1) * A_ + a]);
    u.y = pk2(Wenc[((size_t)h * E_ + kb + 2) * A_ + a], Wenc[((size_t)h * E_ + kb + 3) * A_ + a]);
    u.z = pk2(Wenc[((size_t)h * E_ + kb + 4) * A_ + a], Wenc[((size_t)h * E_ + kb + 5) * A_ + a]);
    u.w = pk2(Wenc[((size_t)h * E_ + kb + 6) * A_ + a], Wenc[((size_t)h * E_ + kb + 7) * A_ + a]);
    ((uint4*)wbs)[c] = u;
  } else if (bid == 128) {
#pragma unroll
    for (int q = 0; q < 4; ++q) {
      const int cw = q * 256 + tid;
      const int h = cw >> 8, cc = cw & 255;
      const int line = cc >> 3, sp = cc & 7;
      const int sraw = sp ^ (line & 7);
      const int a = line * 4 + (sraw >> 1);
      const int s = sraw & 1;
      unsigned short v[8];
#pragma unroll
      for (int j = 0; j < 8; ++j) {
        const int k = s * 8 + j;
        v[j] = (k < C_) ? f2bf(Watt[((size_t)h * C_ + k) * A_ + a]) : (unsigned short)0;
      }
      uint4 u;
      u.x = (unsigned)v[0] | ((unsigned)v[1] << 16);
      u.y = (unsigned)v[2] | ((unsigned)v[3] << 16);
      u.z = (unsigned)v[4] | ((unsigned)v[5] << 16);
      u.w = (unsigned)v[6] | ((unsigned)v[7] << 16);
      ((uint4*)wattb)[cw] = u;
    }
  } else {
    const int idx = bid - 129;
    const int b = idx >> 3, h = (idx >> 1) & 3, ks = idx & 1;
    const int a = tid & 127, kh = tid >> 7;
    const int p = ks * 2 + kh;
    const int d0 = p * 128;
    const float* z = dec_z + (size_t)b * D_ + d0;
    const float* w = Wdec + ((size_t)h * D_ + d0) * A_ + a;
    float s = (p == 0) ? benc[h * A_ + a] : 0.f;
#pragma unroll 8
    for (int d = 0; d < 128; ++d) s += z[d] * w[(size_t)d * A_];
    addv4[(((size_t)p * B_ + b) * H_ + h) * A_ + a] = s;
  }
}

// ---------------------------------------------------------------------------
__global__ __launch_bounds__(256) void k_conv(const float* __restrict__ att_prev,
                                              const float* __restrict__ conv_w,
                                              char* __restrict__ convpad) {
  const int bh = blockIdx.x;
  const int b = bh / H_, h = bh % H_;
  const int t0 = blockIdx.y * 256;
  __shared__ float ap[256 + K_ - 1 + 3];
  __shared__ float cw[C_ * K_];
  const float* src = att_prev + ((size_t)h * B_ + b) * T_;
  for (int i = threadIdx.x; i < 256 + K_ - 1; i += 256) {
    int tt = t0 - (K_ / 2) + i;
    ap[i] = (tt >= 0 && tt < T_) ? src[tt] : 0.f;
  }
  for (int i = threadIdx.x; i < C_ * K_; i += 256) cw[i] = conv_w[(size_t)h * C_ * K_ + i];
  __syncthreads();
  const int t = t0 + threadIdx.x;
  if (t < T_) {
    float s[C_];
#pragma unroll
    for (int c = 0; c < C_; ++c) s[c] = 0.f;
    for (int k = 0; k < K_; ++k) {
      float apv = ap[threadIdx.x + k];
#pragma unroll
      for (int c = 0; c < C_; ++c) s[c] += cw[c * K_ + k] * apv;
    }
    uint4 u0, u1;
    u0.x = pk2(s[0], s[1]); u0.y = pk2(s[2], s[3]);
    u0.z = pk2(s[4], s[5]); u0.w = pk2(s[6], s[7]);
    u1.x = pk2(s[8], s[9]); u1.y = 0u; u1.z = 0u; u1.w = 0u;
    char* dst = convpad + (size_t)(b * T_ + t) * 128 + h * 32;
    *(uint4*)dst = u0;
    *(uint4*)(dst + 16) = u1;
  }
}

// ---------------------------------------------------------------------------
__global__ __launch_bounds__(512, 2) void k_fused_e_mfma(
    const float* __restrict__ enc,
    const char*  __restrict__ wbs,
    const char*  __restrict__ convpad,
    const char*  __restrict__ wattb,
    const float* __restrict__ addv4,
    const float* __restrict__ gv,
    float* __restrict__ e_out) {
  __shared__ char smem[81920];
  const int tid = threadIdx.x;
  const int wv = tid >> 6;
  const int wh = wv & 3;
  const int wm = wv >> 2;
  const int lane = tid & 63;
  const int ln31 = lane & 31;
  const int hi = lane >> 5;
  const int m0 = blockIdx.x * 128;
  const unsigned b0 = (unsigned)m0 / 4000u;
  const unsigned b1 = (unsigned)(m0 + 127) / 4000u;

  f32x16 acc[2][4];
#pragma unroll
  for (int i = 0; i < 2; ++i)
#pragma unroll
    for (int j = 0; j < 4; ++j) acc[i][j] = zero16();

  const int srow = tid >> 2, sksg = tid & 3;
  char* wrA = smem + swz32(srow, sksg);
  const float* encP = enc + (size_t)(m0 + srow) * E_ + sksg * 8;
  const char* wp = wbs + wv * 1024 + lane * 16;
  char* gllB1 = smem + 49152 + wv * 1024;
  char* gllB0 = smem + 16384 + wv * 1024;
  const int aoff = swz32(wm * 64 + ln31, hi);
  const int boff = swz32(wh * 128 + ln31, hi);
  const char* pA  = smem + aoff;
  const char* pAx = smem + (aoff ^ 32);
  const char* pB  = smem + 16384 + boff;
  const char* pBx = smem + 16384 + (boff ^ 32);

#define MSTEP(AOFF, BOFF) do {                                                  \
    { short8 a0_ = *(const short8*)(pA + (AOFF));                               \
      short8 a1_ = *(const short8*)(pA + (AOFF) + 2048);                        \
      short8 b_;                                                                \
      b_ = *(const short8*)(pB + (BOFF));                                       \
      acc[0][0] = MFMA32(a0_, b_, acc[0][0]); acc[1][0] = MFMA32(a1_, b_, acc[1][0]); \
      b_ = *(const short8*)(pB + (BOFF) + 2048);                                \
      acc[0][1] = MFMA32(a0_, b_, acc[0][1]); acc[1][1] = MFMA32(a1_, b_, acc[1][1]); \
      b_ = *(const short8*)(pB + (BOFF) + 4096);                                \
      acc[0][2] = MFMA32(a0_, b_, acc[0][2]); acc[1][2] = MFMA32(a1_, b_, acc[1][2]); \
      b_ = *(const short8*)(pB + (BOFF) + 6144);                                \
      acc[0][3] = MFMA32(a0_, b_, acc[0][3]); acc[1][3] = MFMA32(a1_, b_, acc[1][3]); } \
    { short8 a0_ = *(const short8*)(pAx + (AOFF));                              \
      short8 a1_ = *(const short8*)(pAx + (AOFF) + 2048);                       \
      short8 b_;                                                                \
      b_ = *(const short8*)(pBx + (BOFF));                                      \
      acc[0][0] = MFMA32(a0_, b_, acc[0][0]); acc[1][0] = MFMA32(a1_, b_, acc[1][0]); \
      b_ = *(const short8*)(pBx + (BOFF) + 2048);                               \
      acc[0][1] = MFMA32(a0_, b_, acc[0][1]); acc[1][1] = MFMA32(a1_, b_, acc[1][1]); \
      b_ = *(const short8*)(pBx + (BOFF) + 4096);                               \
      acc[0][2] = MFMA32(a0_, b_, acc[0][2]); acc[1][2] = MFMA32(a1_, b_, acc[1][2]); \
      b_ = *(const short8*)(pBx + (BOFF) + 6144);                               \
      acc[0][3] = MFMA32(a0_, b_, acc[0][3]); acc[1][3] = MFMA32(a1_, b_, acc[1][3]); } \
  } while (0)

#define CBAR(N) do {                                                            \
    asm volatile("s_waitcnt vmcnt(" #N ") lgkmcnt(0)" ::: "memory");            \
    __builtin_amdgcn_sched_barrier(0);                                          \
    __builtin_amdgcn_s_barrier();                                               \
  } while (0)

  float4 rA0, rA1, rB0, rB1;

  // ---- prologue: GLL B0 (oldest), load kt0+kt1 raw, pack kt0 -> A0
#pragma unroll
  for (int it = 0; it < 4; ++it)
    GLL16(wp + it * 8192, gllB0 + it * 8192);
  __builtin_amdgcn_sched_barrier(0);
  {
    float4 t0 = ((const float4*)encP)[0];
    float4 t1 = ((const float4*)encP)[1];
    rA0 = ((const float4*)(encP + 32))[0];
    rA1 = ((const float4*)(encP + 32))[1];
    *(uint4*)wrA = packbf8(t0, t1);
  }
  encP += 64;       // -> kt2
  wp += 32768;      // -> B(kt1) source
  CBAR(2);

#pragma unroll 1
  for (int ktp = 0; ktp < 7; ++ktp) {
    // even kt: MFMA buf0; GLL B(kt+1)->B1; load rB=enc[kt+2]; pack rA->A1
#pragma unroll
    for (int it = 0; it < 4; ++it)
      GLL16(wp + it * 8192, gllB1 + it * 8192);
    __builtin_amdgcn_sched_barrier(0);
    rB0 = ((const float4*)encP)[0];
    rB1 = ((const float4*)encP)[1];
    __builtin_amdgcn_sched_barrier(0);
    MSTEP(0, 0);
    *(uint4*)(wrA + 8192) = packbf8(rA0, rA1);
    encP += 32; wp += 32768;
    CBAR(2);
    // odd kt: MFMA buf1; GLL->B0; load rA=enc[kt+2]; pack rB->A0
#pragma unroll
    for (int it = 0; it < 4; ++it)
      GLL16(wp + it * 8192, gllB0 + it * 8192);
    __builtin_amdgcn_sched_barrier(0);
    rA0 = ((const float4*)encP)[0];
    rA1 = ((const float4*)encP)[1];
    __builtin_amdgcn_sched_barrier(0);
    MSTEP(8192, 32768);
    *(uint4*)wrA = packbf8(rB0, rB1);
    encP += 32; wp += 32768;
    CBAR(2);
  }

  // kt=14: MFMA buf0; GLL B15->B1; pack rA(enc kt15)->A1; drain
#pragma unroll
  for (int it = 0; it < 4; ++it)
    GLL16(wp + it * 8192, gllB1 + it * 8192);
  __builtin_amdgcn_sched_barrier(0);
  MSTEP(0, 0);
  *(uint4*)(wrA + 8192) = packbf8(rA0, rA1);
  CBAR(0);

  // kt=15: MFMA buf1; GLL Watt->smem+32768; stage conv/addv/gv; drain
  {
#pragma unroll
    for (int it = 0; it < 2; ++it)
      GLL16(wattb + (size_t)it * 8192 + wv * 1024 + lane * 16, gllB0 + 16384 + it * 8192);
    __builtin_amdgcn_sched_barrier(0);
    uint4 rc0 = *(const uint4*)(convpad + (size_t)(m0 + (tid >> 3)) * 128 + (tid & 7) * 16);
    uint4 rc1 = *(const uint4*)(convpad + (size_t)(m0 + ((tid + 512) >> 3)) * 128 + (tid & 7) * 16);
    float av0s = addv4[b0 * 512 + tid]         + addv4[8192 + b0 * 512 + tid]
               + addv4[16384 + b0 * 512 + tid] + addv4[24576 + b0 * 512 + tid];
    float av1s = addv4[b1 * 512 + tid]         + addv4[8192 + b1 * 512 + tid]
               + addv4[16384 + b1 * 512 + tid] + addv4[24576 + b1 * 512 + tid];
    float gvv = gv[tid];
    __builtin_amdgcn_sched_barrier(0);
    MSTEP(8192, 32768);
    *(uint4*)(smem + 16384 + swzC(tid >> 3, tid & 7)) = rc0;
    *(uint4*)(smem + 16384 + swzC((tid + 512) >> 3, tid & 7)) = rc1;
    ((float*)smem)[tid] = av0s;
    ((float*)smem)[512 + tid] = av1s;
    ((float*)smem)[1024 + tid] = gvv;
    CBAR(0);
  }

  // conv MFMA step (K=16): A = conv features, B = Watt
  {
    const char* AconvL = smem + 16384;
    const char* WattL  = smem + 32768;
    const int sl = wh * 2 + hi;
    short8 ac0 = *(const short8*)(AconvL + swzC(wm * 64 + ln31, sl));
    short8 ac1 = *(const short8*)(AconvL + swzC(wm * 64 + 32 + ln31, sl));
#pragma unroll
    for (int ni = 0; ni < 4; ++ni) {
      const int a = ni * 32 + ln31;
      short8 wf = *(const short8*)(WattL + wh * 4096 + (a >> 2) * 128 +
                                   (((((a & 3) << 1) | hi) ^ ((a >> 2) & 7)) << 4));
      acc[0][ni] = MFMA32(ac0, wf, acc[0][ni]);
      acc[1][ni] = MFMA32(ac1, wf, acc[1][ni]);
    }
  }

  // epilogue
  {
    const float* An_f = (const float*)smem;
    float av0[4], av1[4], gvr[4];
#pragma unroll
    for (int ni = 0; ni < 4; ++ni) {
      const int a = wh * 128 + ni * 32 + ln31;
      av0[ni] = An_f[a];
      av1[ni] = An_f[512 + a];
      gvr[ni] = An_f[1024 + a];
    }
#pragma unroll
    for (int mi = 0; mi < 2; ++mi) {
#pragma unroll
      for (int reg = 0; reg < 16; ++reg) {
        const int rl = wm * 64 + mi * 32 + (reg & 3) + ((reg >> 2) << 3) + (hi << 2);
        const unsigned brow = (unsigned)(m0 + rl);
        const unsigned bb = brow / 4000u;
        const unsigned tt = brow - bb * 4000u;
        const int sel = (bb != b0);
        float rs = 0.f;
#pragma unroll
        for (int ni = 0; ni < 4; ++ni) {
          float s = acc[mi][ni][reg] + (sel ? av1[ni] : av0[ni]);
          rs += gvr[ni] * tanh_fast(s);
        }
        rs += __shfl_xor(rs, 1);
        rs += __shfl_xor(rs, 2);
        rs += __shfl_xor(rs, 4);
        rs += __shfl_xor(rs, 8);
        rs += __shfl_xor(rs, 16);
        if (ln31 == 0) e_out[((size_t)bb * H_ + wh) * T_ + tt] = rs;
      }
    }
  }
#undef MSTEP
#undef CBAR
}

// ---------------------------------------------------------------------------
__global__ __launch_bounds__(256) void k_msum(const float* __restrict__ e_in,
                                              float2* __restrict__ msum) {
  const int bh = blockIdx.x;
  const float* er = e_in + (size_t)bh * T_;
  __shared__ float red[256];
  const int tid = threadIdx.x;
  float m = -1e30f;
  for (int t = tid; t < T_; t += 256) m = fmaxf(m, er[t]);
  red[tid] = m;
  __syncthreads();
  for (int s = 128; s > 0; s >>= 1) {
    if (tid < s) red[tid] = fmaxf(red[tid], red[tid + s]);
    __syncthreads();
  }
  m = red[0];
  __syncthreads();
  float sum = 0.f;
  for (int t = tid; t < T_; t += 256) sum += __expf(er[t] - m);
  red[tid] = sum;
  __syncthreads();
  for (int s = 128; s > 0; s >>= 1) {
    if (tid < s) red[tid] += red[tid + s];
    __syncthreads();
  }
  if (tid == 0) msum[bh] = make_float2(m, 1.0f / red[0]);
}

// ---------------------------------------------------------------------------
__global__ __launch_bounds__(128) void k_ctx(const float* __restrict__ enc,
                                             const float* __restrict__ e_in,
                                             const float2* __restrict__ msum,
                                             float* __restrict__ wout,
                                             float* __restrict__ partial) {
  const int b = blockIdx.x, tc = blockIdx.y;
  const int t0 = tc * CH_;
  const int tid = threadIdx.x;
  __shared__ float wls[H_ * CH_];
  for (int i = tid; i < H_ * CH_; i += 128) {
    const int h = i / CH_, tt = i - h * CH_;
    const float2 ms = msum[b * H_ + h];
    const float w = __expf(e_in[((size_t)b * H_ + h) * T_ + t0 + tt] - ms.x) * ms.y;
    wls[i] = w;
    wout[((size_t)h * B_ + b) * T_ + t0 + tt] = w;
  }
  __syncthreads();
  float4 a0 = {0,0,0,0}, a1 = {0,0,0,0}, a2 = {0,0,0,0}, a3 = {0,0,0,0};
  const float4* enc4 = (const float4*)enc;
  const size_t ebase = ((size_t)b * T_ + t0) * 128 + tid;
#pragma unroll 8
  for (int tt = 0; tt < CH_; ++tt) {
    const float4 x = enc4[ebase + (size_t)tt * 128];
    const float w0 = wls[tt], w1 = wls[CH_ + tt], w2 = wls[2 * CH_ + tt], w3 = wls[3 * CH_ + tt];
    a0.x += w0 * x.x; a0.y += w0 * x.y; a0.z += w0 * x.z; a0.w += w0 * x.w;
    a1.x += w1 * x.x; a1.y += w1 * x.y; a1.z += w1 * x.z; a1.w += w1 * x.w;
    a2.x += w2 * x.x; a2.y += w2 * x.y; a2.z += w2 * x.z; a2.w += w2 * x.w;
    a3.x += w3 * x.x; a3.y += w3 * x.y; a3.z += w3 * x.z; a3.w += w3 * x.w;
  }
  float4* p4 = (float4*)partial;
  const size_t pbase = (((size_t)tc * B_ + b) * H_) * 128 + tid;
  p4[pbase] = a0;
  p4[pbase + 128] = a1;
  p4[pbase + 256] = a2;
  p4[pbase + 384] = a3;
}

// ---------------------------------------------------------------------------
__global__ __launch_bounds__(256) void k_out_part(const float* __restrict__ partial,
                                                  const float* __restrict__ Wo,
                                                  float* __restrict__ p2) {
  const int b = blockIdx.x;
  const int o = blockIdx.y * 256 + threadIdx.x;
  const int kc = blockIdx.z;
  __shared__ float cS[256];
  const int he0 = kc * 256;
  {
    float s = 0.f;
#pragma unroll
    for (int tc = 0; tc < TC_; ++tc)
      s += partial[((size_t)tc * B_ + b) * (H_ * E_) + he0 + threadIdx.x];
    cS[threadIdx.x] = s;
  }
  __syncthreads();
  float s = 0.f;
#pragma unroll 8
  for (int i = 0; i < 256; ++i) s += cS[i] * Wo[(size_t)(he0 + i) * O_ + o];
  p2[((size_t)kc * B_ + b) * O_ + o] = s;
}

__global__ __launch_bounds__(512) void k_out_fin(const float* __restrict__ p2,
                                                 const float* __restrict__ bo,
                                                 float* __restrict__ out) {
  const int b = blockIdx.x, o = threadIdx.x;
  float s = bo[o];
#pragma unroll
  for (int kc = 0; kc < 8; ++kc) s += p2[((size_t)kc * B_ + b) * O_ + o];
  out[b * O_ + o] = s;
}

// ---------------------------------------------------------------------------
extern "C" void kernel_launch(void* const* d_in, const int* in_sizes, int n_in,
                              void* d_out, int out_size, void* d_ws, size_t ws_size,
                              hipStream_t stream) {
  (void)in_sizes; (void)n_in; (void)out_size; (void)ws_size;
  const float* enc      = (const float*)d_in[0];
  // d_in[1] = enc_len : unused by the reference
  const float* dec_z    = (const float*)d_in[2];
  const float* att_prev = (const float*)d_in[3];
  const float* Wenc     = (const float*)d_in[4];
  const float* benc     = (const float*)d_in[5];
  const float* Wdec     = (const float*)d_in[6];
  const float* Watt     = (const float*)d_in[7];
  const float* conv_w   = (const float*)d_in[8];
  const float* gv       = (const float*)d_in[9];
  const float* Wo       = (const float*)d_in[10];
  const float* bo       = (const float*)d_in[11];

  float* out  = (float*)d_out;
  float* wout = out + B_ * O_;  // ws [H,B,T]

  char* wsb = (char*)d_ws;
  float*  e_buf   = (float*)(wsb);               // 1,024,000 B
  char*   convpad = wsb + 1024000;               // 8,192,000 B
  char*   wbs     = wsb + 9216000;               //   524,288 B
  char*   wattb   = wsb + 9740288;               //    16,384 B
  float*  addv4   = (float*)(wsb + 9756672);     //   131,072 B
  float2* msum    = (float2*)(wsb + 9887744);    //       512 B
  float*  partial = (float*)(wsb + 9888256);     // 6,553,600 B
  float*  p2      = (float*)(wsb + 16441856);    //   262,144 B

  hipLaunchKernelGGL(k_prep, dim3(257), dim3(256), 0, stream,
                     Wenc, Watt, dec_z, Wdec, benc, wbs, wattb, addv4);
  hipLaunchKernelGGL(k_conv, dim3(B_ * H_, 16), dim3(256), 0, stream, att_prev, conv_w, convpad);
  hipLaunchKernelGGL(k_fused_e_mfma, dim3(500), dim3(512), 0, stream,
                     enc, wbs, convpad, wattb, addv4, gv, e_buf);
  hipLaunchKernelGGL(k_msum, dim3(B_ * H_), dim3(256), 0, stream, e_buf, msum);
  hipLaunchKernelGGL(k_ctx, dim3(B_, TC_), dim3(128), 0, stream, enc, e_buf, msum, wout, partial);
  hipLaunchKernelGGL(k_out_part, dim3(B_, O_ / 256, 8), dim3(256), 0, stream, partial, Wo, p2);
  hipLaunchKernelGGL(k_out_fin, dim3(B_), dim3(512), 0, stream, p2, bo, out);
}